// Round 19
// baseline (303.361 us; speedup 1.0000x reference)
//
#include <hip/hip_runtime.h>
#include <math.h>

#define N_NODES 50000
#define N_EDGES 1600000
#define DIM 64
#define HEADS 8
#define EDGE_DIM 32

#define NB 256      // destination buckets
#define NPB 196     // nodes per bucket (196*256 = 50176 >= 50000)
#define ACAP 8192   // per-bucket capacity (mean 6250, sd ~79 -> 24 sigma)
#define PART_T 256
#define EPT 8
#define PART_E (PART_T * EPT)  // 2048 edges per partition block

#define QKV_BLKS 12500  // ceil(N_NODES/4)

typedef __fp16 h2 __attribute__((ext_vector_type(2)));

// ---- bf16 / h2 helpers ----
__device__ __forceinline__ unsigned int f2bf(float f) {
    union { float f; unsigned int u; } c; c.f = f;
    unsigned int u = c.u;
    return (u + 0x7FFFu + ((u >> 16) & 1u)) >> 16;
}
__device__ __forceinline__ float bf_lo(unsigned int u) { return __uint_as_float(u << 16); }
__device__ __forceinline__ float bf_hi(unsigned int u) { return __uint_as_float(u & 0xFFFF0000u); }
__device__ __forceinline__ unsigned int h2u(h2 v) { union { h2 h; unsigned int u; } c; c.h = v; return c.u; }
__device__ __forceinline__ h2 u2h(unsigned int x) { union { h2 h; unsigned int u; } c; c.u = x; return c.h; }

// ---------------- K_prep: pack MLP weights + zero bucket cursors ----------------
__global__ __launch_bounds__(1024) void pack_weights(
    const float* __restrict__ We1, const float* __restrict__ We2,
    h2* __restrict__ w1p, h2* __restrict__ w2p, int* __restrict__ gcur)
{
    const int t = threadIdx.x;
    if (t < 512) {
        const int c = t >> 4, kk = t & 15;
        w1p[t] = __builtin_amdgcn_cvt_pkrtz(We1[(2 * kk) * EDGE_DIM + c],
                                            We1[(2 * kk + 1) * EDGE_DIM + c]);
    } else if (t < 512 + 128) {
        const int u = t - 512;
        const int h = u >> 4, cc = u & 15;
        w2p[u] = __builtin_amdgcn_cvt_pkrtz(We2[(2 * cc) * HEADS + h],
                                            We2[(2 * cc + 1) * HEADS + h]);
    } else if (t >= 768 && t < 768 + NB) {
        gcur[t - 768] = 0;
    }
}

// ---------------- K_A1: streaming edge MLP -> bias_by_e (no LDS, no barriers) ----------------
__global__ __launch_bounds__(256) void mlp_only(
    const float* __restrict__ edge_attr,
    const h2* __restrict__ w1p, const float* __restrict__ be1,
    const h2* __restrict__ w2p, const float* __restrict__ be2,
    uint4* __restrict__ bias_by_e)
{
    const int e = blockIdx.x * 256 + threadIdx.x;
    if (e >= N_EDGES) return;
    float a[EDGE_DIM];
    const float4* ar = (const float4*)(edge_attr + (size_t)e * EDGE_DIM);
    #pragma unroll
    for (int q = 0; q < EDGE_DIM / 4; ++q) {
        float4 v = ar[q];
        a[q * 4 + 0] = v.x; a[q * 4 + 1] = v.y;
        a[q * 4 + 2] = v.z; a[q * 4 + 3] = v.w;
    }
    h2 a2[EDGE_DIM / 2];
    #pragma unroll
    for (int kk = 0; kk < EDGE_DIM / 2; ++kk)
        a2[kk] = __builtin_amdgcn_cvt_pkrtz(a[2 * kk], a[2 * kk + 1]);
    float sil[EDGE_DIM];
    #pragma unroll 8
    for (int c = 0; c < EDGE_DIM; ++c) {
        float s = be1[c];
        #pragma unroll
        for (int kk = 0; kk < EDGE_DIM / 2; ++kk)
            s = __builtin_amdgcn_fdot2(a2[kk], w1p[c * 16 + kk], s, false);
        sil[c] = __fdividef(s, 1.0f + __expf(-s));
    }
    h2 s2[EDGE_DIM / 2];
    #pragma unroll
    for (int cc = 0; cc < EDGE_DIM / 2; ++cc)
        s2[cc] = __builtin_amdgcn_cvt_pkrtz(sil[2 * cc], sil[2 * cc + 1]);
    float b0f = be2[0], b1f = be2[1], b2f = be2[2], b3f = be2[3];
    float b4f = be2[4], b5f = be2[5], b6f = be2[6], b7f = be2[7];
    #pragma unroll
    for (int cc = 0; cc < EDGE_DIM / 2; ++cc) {
        b0f = __builtin_amdgcn_fdot2(s2[cc], w2p[0 * 16 + cc], b0f, false);
        b1f = __builtin_amdgcn_fdot2(s2[cc], w2p[1 * 16 + cc], b1f, false);
        b2f = __builtin_amdgcn_fdot2(s2[cc], w2p[2 * 16 + cc], b2f, false);
        b3f = __builtin_amdgcn_fdot2(s2[cc], w2p[3 * 16 + cc], b3f, false);
        b4f = __builtin_amdgcn_fdot2(s2[cc], w2p[4 * 16 + cc], b4f, false);
        b5f = __builtin_amdgcn_fdot2(s2[cc], w2p[5 * 16 + cc], b5f, false);
        b6f = __builtin_amdgcn_fdot2(s2[cc], w2p[6 * 16 + cc], b6f, false);
        b7f = __builtin_amdgcn_fdot2(s2[cc], w2p[7 * 16 + cc], b7f, false);
    }
    uint4 br;
    br.x = f2bf(b0f) | (f2bf(b1f) << 16);
    br.y = f2bf(b2f) | (f2bf(b3f) << 16);
    br.z = f2bf(b4f) | (f2bf(b5f) << 16);
    br.w = f2bf(b6f) | (f2bf(b7f) << 16);
    bias_by_e[e] = br;
}

// ---------------- K_A2: 8B-record bucket partition (shfl scans, few barriers) ----------------
__global__ __launch_bounds__(256) void partition_only(
    const int* __restrict__ ei, int* __restrict__ gcur, uint2* __restrict__ A_rec)
{
    __shared__ int cnt[NB];
    __shared__ int base[NB];
    __shared__ int lbase[NB];
    __shared__ int wsum[4];
    __shared__ int total_s;
    __shared__ uint2 srec[PART_E];          // 16 KB
    __shared__ unsigned char sbkt[PART_E];  // 2 KB
    const int tid = threadIdx.x;
    const int lane = tid & 63;
    const int w = tid >> 6;
    cnt[tid] = 0;
    __syncthreads();
    const int e0 = blockIdx.x * PART_E;
    #pragma unroll
    for (int k = 0; k < EPT; ++k) {
        const int e = e0 + k * PART_T + tid;
        if (e < N_EDGES) atomicAdd(&cnt[ei[N_EDGES + e] / NPB], 1);
    }
    __syncthreads();
    // wave-shfl inclusive scan of cnt (2 barriers total)
    int v = cnt[tid];
    #pragma unroll
    for (int o = 1; o < 64; o <<= 1) {
        int t = __shfl_up(v, o, 64);
        if (lane >= o) v += t;
    }
    if (lane == 63) wsum[w] = v;
    __syncthreads();
    int add = 0;
    #pragma unroll
    for (int ww = 0; ww < 3; ++ww) if (ww < w) add += wsum[ww];
    v += add;  // inclusive scan
    {
        const int c = cnt[tid];
        base[tid] = (c > 0) ? atomicAdd(&gcur[tid], c) : 0;
        lbase[tid] = v - c;  // exclusive
        if (tid == NB - 1) total_s = v;
        cnt[tid] = 0;        // reuse as local cursor
    }
    __syncthreads();
    #pragma unroll
    for (int k = 0; k < EPT; ++k) {
        const int e = e0 + k * PART_T + tid;
        if (e < N_EDGES) {
            const int i = ei[e];
            const int j = ei[N_EDGES + e];
            const int b = j / NPB;
            const int jl = j - b * NPB;
            const int s = lbase[b] + atomicAdd(&cnt[b], 1);
            srec[s] = make_uint2((unsigned)e, ((unsigned)jl << 24) | (unsigned)i);
            sbkt[s] = (unsigned char)b;
        }
    }
    __syncthreads();
    const int total = total_s;
    for (int s = tid; s < total; s += PART_T) {
        const int b = sbkt[s];
        const int gp = base[b] + (s - lbase[b]);
        if (gp < ACAP) A_rec[(size_t)b * ACAP + gp] = srec[s];
    }
}

// ---------------- K_B: heterogeneous grid — perm+bias-move (blocks 0..NB-1) + qkv ----------------
// perm now ALSO copies bias_by_e[e] -> bias_sorted[pos] (random gather hides under
// the perm machinery; attn then streams bias sequentially).
__global__ __launch_bounds__(256) void perm_qkv(
    const int* __restrict__ gcur, const uint2* __restrict__ A_rec,
    const uint4* __restrict__ bias_by_e,
    int* __restrict__ offs, int* __restrict__ src_sorted,
    uint4* __restrict__ bias_sorted,
    const float* __restrict__ x,
    const float* __restrict__ WQ, const float* __restrict__ bQ,
    const float* __restrict__ WK, const float* __restrict__ bK,
    const float* __restrict__ WV, const float* __restrict__ bV,
    unsigned int* __restrict__ Q2, unsigned int* __restrict__ KV2)
{
    __shared__ __align__(16) char smem[3 * DIM * DIM * sizeof(float)];  // 48 KB
    const int tid = threadIdx.x;
    const int lane = tid & 63;
    const int w = tid >> 6;
    if (blockIdx.x < NB) {
        int* ldeg = (int*)smem;          // NPB
        int* loff = ldeg + NPB;          // NPB+1
        int* wsum = loff + NPB + 1;      // 4
        int* gb   = wsum + 4;            // 1
        const int b = blockIdx.x;
        // gbase = prefix sum of min(gcur[t],ACAP) for t < b (single wave)
        if (w == 0) {
            int ssum = 0;
            for (int t = lane; t < b; t += 64) ssum += min(gcur[t], ACAP);
            #pragma unroll
            for (int o = 1; o < 64; o <<= 1) ssum += __shfl_xor(ssum, o, 64);
            if (lane == 0) gb[0] = ssum;
        }
        if (tid < NPB) ldeg[tid] = 0;
        __syncthreads();
        const int gbase = gb[0];
        const int nb = min(gcur[b], ACAP);
        for (int r = tid; r < nb; r += 256)
            atomicAdd(&ldeg[A_rec[(size_t)b * ACAP + r].y >> 24], 1);
        __syncthreads();
        // wave-shfl scan of ldeg (padded to 256)
        int v = (tid < NPB) ? ldeg[tid] : 0;
        #pragma unroll
        for (int o = 1; o < 64; o <<= 1) {
            int t = __shfl_up(v, o, 64);
            if (lane >= o) v += t;
        }
        if (lane == 63) wsum[w] = v;
        __syncthreads();
        int add = 0;
        #pragma unroll
        for (int ww = 0; ww < 3; ++ww) if (ww < w) add += wsum[ww];
        v += add;
        if (tid == 0) loff[0] = 0;
        if (tid < NPB) { loff[tid + 1] = v; ldeg[tid] = 0; }  // ldeg -> cursor
        __syncthreads();
        const int jbase = b * NPB;
        if (tid < NPB && jbase + tid < N_NODES) offs[jbase + tid] = gbase + loff[tid];
        if (b == NB - 1 && tid == 0) offs[N_NODES] = gbase + nb;
        for (int r = tid; r < nb; r += 256) {
            const uint2 rec = A_rec[(size_t)b * ACAP + r];
            const int jl = (int)(rec.y >> 24);
            const int slot = loff[jl] + atomicAdd(&ldeg[jl], 1);
            const int gp = gbase + slot;
            src_sorted[gp] = (int)(rec.y & 0xFFFFFFu);
            bias_sorted[gp] = bias_by_e[rec.x];  // random 16B gather, L2-window write
        }
    } else {
        float* sWQ = (float*)smem;
        float* sWK = sWQ + DIM * DIM;
        float* sWV = sWK + DIM * DIM;
        for (int t = tid; t < DIM * DIM; t += 256) {
            sWQ[t] = WQ[t]; sWK[t] = WK[t]; sWV[t] = WV[t];
        }
        __syncthreads();
        const int n = (blockIdx.x - NB) * 4 + w;
        if (n >= N_NODES) return;
        float xl = x[(size_t)n * DIM + lane];
        float aq = bQ[lane], ak = bK[lane], av = bV[lane];
        #pragma unroll
        for (int k = 0; k < DIM; ++k) {
            float xv = __shfl(xl, k, 64);
            aq += xv * sWQ[k * DIM + lane];
            ak += xv * sWK[k * DIM + lane];
            av += xv * sWV[k * DIM + lane];
        }
        const int s = lane & 31;
        const float aq_e = __shfl(aq, 2 * s, 64);
        const float aq_o = __shfl(aq, 2 * s + 1, 64);
        const float ak_e = __shfl(ak, 2 * s, 64);
        const float ak_o = __shfl(ak, 2 * s + 1, 64);
        const float av_e = __shfl(av, 2 * s, 64);
        const float av_o = __shfl(av, 2 * s + 1, 64);
        if (lane < 32) {
            Q2[(size_t)n * 32 + s]  = h2u(__builtin_amdgcn_cvt_pkrtz(aq_e, aq_o));
            KV2[(size_t)n * 64 + s] = h2u(__builtin_amdgcn_cvt_pkrtz(ak_e, ak_o));
        } else {
            KV2[(size_t)n * 64 + 32 + s] = f2bf(av_e) | (f2bf(av_o) << 16);
        }
    }
}

// ---------------- K3: per-node attention + fused out-proj, paired-dim fdot2 ----------------
// src and bias now both STREAM in sorted order; only the KV gather is random.
__global__ __launch_bounds__(256) void node_attn_out(
    const int* __restrict__ off,
    const int* __restrict__ src_sorted,
    const unsigned short* __restrict__ bias_u16,  // = bias_sorted, sequential
    const unsigned int* __restrict__ Q2, const unsigned int* __restrict__ KV2,
    const float* __restrict__ WO, const float* __restrict__ bO,
    float* __restrict__ out)
{
    __shared__ float sWO[DIM * DIM];
    for (int t = threadIdx.x; t < DIM * DIM; t += 256) sWO[t] = WO[t];
    __syncthreads();
    const int lane = threadIdx.x & 63;
    const int wave = threadIdx.x >> 6;
    const int j = blockIdx.x * 4 + wave;
    if (j >= N_NODES) return;
    const int beg = off[j], end = off[j + 1];
    const int s = lane & 31;
    const int half = lane >> 5;
    const int h = s >> 2;
    const float inv_sqrt_dk = 0.35355339059327373f;
    const h2 q2 = u2h(Q2[(size_t)j * 32 + s]);
    float num2x = 0.0f, num2y = 0.0f;
    float den = 1e-12f;
    int t = beg;
    for (; t + 7 < end; t += 8) {
        int iv[4];
        unsigned int k2v[4], v2v[4];
        float bb[4], d[4];
        #pragma unroll
        for (int q = 0; q < 4; ++q) iv[q] = src_sorted[t + 2 * q + half];
        #pragma unroll
        for (int q = 0; q < 4; ++q) k2v[q] = KV2[(size_t)iv[q] * 64 + s];
        #pragma unroll
        for (int q = 0; q < 4; ++q) v2v[q] = KV2[(size_t)iv[q] * 64 + 32 + s];
        #pragma unroll
        for (int q = 0; q < 4; ++q)
            bb[q] = bf_lo((unsigned int)bias_u16[(size_t)(t + 2 * q + half) * HEADS + h]);
        #pragma unroll
        for (int q = 0; q < 4; ++q)
            d[q] = __builtin_amdgcn_fdot2(q2, u2h(k2v[q]), 0.0f, false);
        #pragma unroll
        for (int q = 0; q < 4; ++q) d[q] += __shfl_xor(d[q], 1, 64);
        #pragma unroll
        for (int q = 0; q < 4; ++q) d[q] += __shfl_xor(d[q], 2, 64);
        #pragma unroll
        for (int q = 0; q < 4; ++q) {
            const float ev = __expf(d[q] * inv_sqrt_dk + bb[q]);
            num2x += ev * bf_lo(v2v[q]);
            num2y += ev * bf_hi(v2v[q]);
            den += ev;
        }
    }
    for (; t + 1 < end; t += 2) {
        const int iv = src_sorted[t + half];
        const unsigned int k2v = KV2[(size_t)iv * 64 + s];
        const unsigned int v2v = KV2[(size_t)iv * 64 + 32 + s];
        const float bb = bf_lo((unsigned int)bias_u16[(size_t)(t + half) * HEADS + h]);
        float d = __builtin_amdgcn_fdot2(q2, u2h(k2v), 0.0f, false);
        d += __shfl_xor(d, 1, 64);
        d += __shfl_xor(d, 2, 64);
        const float ev = __expf(d * inv_sqrt_dk + bb);
        num2x += ev * bf_lo(v2v);
        num2y += ev * bf_hi(v2v);
        den += ev;
    }
    if (t < end) {  // odd tail: only half 0 contributes
        const int iv = src_sorted[t];
        const unsigned int k2v = KV2[(size_t)iv * 64 + s];
        const unsigned int v2v = KV2[(size_t)iv * 64 + 32 + s];
        const float bb = bf_lo((unsigned int)bias_u16[(size_t)t * HEADS + h]);
        float d = __builtin_amdgcn_fdot2(q2, u2h(k2v), 0.0f, false);
        d += __shfl_xor(d, 1, 64);
        d += __shfl_xor(d, 2, 64);
        float ev = __expf(d * inv_sqrt_dk + bb);
        if (half != 0) ev = 0.0f;
        num2x += ev * bf_lo(v2v);
        num2y += ev * bf_hi(v2v);
        den += ev;
    }
    num2x += __shfl_xor(num2x, 32, 64);
    num2y += __shfl_xor(num2y, 32, 64);
    den   += __shfl_xor(den, 32, 64);
    const float av2x = num2x / den;
    const float av2y = num2y / den;
    float acc = bO[lane];
    #pragma unroll
    for (int sp = 0; sp < 32; ++sp) {
        acc += __shfl(av2x, sp, 64) * sWO[(2 * sp) * DIM + lane];
        acc += __shfl(av2y, sp, 64) * sWO[(2 * sp + 1) * DIM + lane];
    }
    out[(size_t)j * DIM + lane] = acc;
}

extern "C" void kernel_launch(void* const* d_in, const int* in_sizes, int n_in,
                              void* d_out, int out_size, void* d_ws, size_t ws_size,
                              hipStream_t stream) {
    const float* x    = (const float*)d_in[0];
    const int*   ei   = (const int*)d_in[1];
    const float* ea   = (const float*)d_in[2];
    const float* WQ   = (const float*)d_in[3];
    const float* bQ   = (const float*)d_in[4];
    const float* WK   = (const float*)d_in[5];
    const float* bK   = (const float*)d_in[6];
    const float* WV   = (const float*)d_in[7];
    const float* bV   = (const float*)d_in[8];
    const float* WO   = (const float*)d_in[9];
    const float* bO   = (const float*)d_in[10];
    const float* We1  = (const float*)d_in[11];
    const float* be1  = (const float*)d_in[12];
    const float* We2  = (const float*)d_in[13];
    const float* be2  = (const float*)d_in[14];
    float* out = (float*)d_out;

    char* ws = (char*)d_ws;
    size_t off_b = 0;
    auto alloc = [&](size_t bytes) {
        void* p = ws + off_b;
        off_b += (bytes + 255) & ~(size_t)255;
        return p;
    };
    unsigned int* Q2          = (unsigned int*)alloc((size_t)N_NODES * 32 * sizeof(unsigned int));
    unsigned int* KV2         = (unsigned int*)alloc((size_t)N_NODES * 64 * sizeof(unsigned int));
    uint2*        A_rec       = (uint2*)alloc((size_t)NB * ACAP * sizeof(uint2));
    uint4*        bias_by_e   = (uint4*)alloc((size_t)N_EDGES * sizeof(uint4));
    uint4*        bias_sorted = (uint4*)alloc((size_t)N_EDGES * sizeof(uint4));
    int*          src_sorted  = (int*)alloc((size_t)N_EDGES * sizeof(int));
    int*          offs        = (int*)alloc((size_t)(N_NODES + 1) * sizeof(int));
    int*          gcur        = (int*)alloc((size_t)NB * sizeof(int));
    h2*           w1p         = (h2*)alloc(512 * sizeof(h2));
    h2*           w2p         = (h2*)alloc(128 * sizeof(h2));

    pack_weights<<<1, 1024, 0, stream>>>(We1, We2, w1p, w2p, gcur);
    partition_only<<<(N_EDGES + PART_E - 1) / PART_E, PART_T, 0, stream>>>(ei, gcur, A_rec);
    mlp_only<<<(N_EDGES + 255) / 256, 256, 0, stream>>>(ea, w1p, be1, w2p, be2, bias_by_e);
    perm_qkv<<<NB + QKV_BLKS, 256, 0, stream>>>(gcur, A_rec, bias_by_e,
                                                offs, src_sorted, bias_sorted,
                                                x, WQ, bQ, WK, bK, WV, bV, Q2, KV2);
    node_attn_out<<<(N_NODES + 3) / 4, 256, 0, stream>>>(offs, src_sorted,
                                                         (const unsigned short*)bias_sorted,
                                                         Q2, KV2, WO, bO, out);
}

// Round 20
// 291.107 us; speedup vs baseline: 1.0421x; 1.0421x over previous
//
#include <hip/hip_runtime.h>
#include <math.h>

#define N_NODES 50000
#define N_EDGES 1600000
#define DIM 64
#define HEADS 8
#define EDGE_DIM 32

#define NB 512      // destination buckets
#define NPB 98      // nodes per bucket (98*512 = 50176 >= 50000)
#define ACAP 4096   // per-bucket capacity (mean 3125, sd ~56 -> 17 sigma)
#define PART_T 512
#define EPT 4
#define PART_E (PART_T * EPT)  // 2048 edges per partition block

#define QKV_BLKS 12500  // ceil(N_NODES/4)

typedef __fp16 h2 __attribute__((ext_vector_type(2)));

// ---- bf16 / h2 helpers ----
__device__ __forceinline__ unsigned int f2bf(float f) {
    union { float f; unsigned int u; } c; c.f = f;
    unsigned int u = c.u;
    return (u + 0x7FFFu + ((u >> 16) & 1u)) >> 16;
}
__device__ __forceinline__ float bf_lo(unsigned int u) { return __uint_as_float(u << 16); }
__device__ __forceinline__ float bf_hi(unsigned int u) { return __uint_as_float(u & 0xFFFF0000u); }
__device__ __forceinline__ unsigned int h2u(h2 v) { union { h2 h; unsigned int u; } c; c.h = v; return c.u; }
__device__ __forceinline__ h2 u2h(unsigned int x) { union { h2 h; unsigned int u; } c; c.u = x; return c.h; }

// ---------------- K_prep: pack MLP weights + zero bucket cursors ----------------
__global__ __launch_bounds__(1024) void pack_weights(
    const float* __restrict__ We1, const float* __restrict__ We2,
    h2* __restrict__ w1p, h2* __restrict__ w2p, int* __restrict__ gcur)
{
    const int t = threadIdx.x;
    if (t < 512) {
        const int c = t >> 4, kk = t & 15;
        w1p[t] = __builtin_amdgcn_cvt_pkrtz(We1[(2 * kk) * EDGE_DIM + c],
                                            We1[(2 * kk + 1) * EDGE_DIM + c]);
    } else if (t < 512 + 128) {
        const int u = t - 512;
        const int h = u >> 4, cc = u & 15;
        w2p[u] = __builtin_amdgcn_cvt_pkrtz(We2[(2 * cc) * HEADS + h],
                                            We2[(2 * cc + 1) * HEADS + h]);
    }
    if (t < NB) gcur[t] = 0;
}

// ---------------- K_A1: streaming edge MLP -> bias_by_e (no LDS, no barriers) ----------------
__global__ __launch_bounds__(256) void mlp_only(
    const float* __restrict__ edge_attr,
    const h2* __restrict__ w1p, const float* __restrict__ be1,
    const h2* __restrict__ w2p, const float* __restrict__ be2,
    uint4* __restrict__ bias_by_e)
{
    const int e = blockIdx.x * 256 + threadIdx.x;
    if (e >= N_EDGES) return;
    float a[EDGE_DIM];
    const float4* ar = (const float4*)(edge_attr + (size_t)e * EDGE_DIM);
    #pragma unroll
    for (int q = 0; q < EDGE_DIM / 4; ++q) {
        float4 v = ar[q];
        a[q * 4 + 0] = v.x; a[q * 4 + 1] = v.y;
        a[q * 4 + 2] = v.z; a[q * 4 + 3] = v.w;
    }
    h2 a2[EDGE_DIM / 2];
    #pragma unroll
    for (int kk = 0; kk < EDGE_DIM / 2; ++kk)
        a2[kk] = __builtin_amdgcn_cvt_pkrtz(a[2 * kk], a[2 * kk + 1]);
    float sil[EDGE_DIM];
    #pragma unroll 8
    for (int c = 0; c < EDGE_DIM; ++c) {
        float s = be1[c];
        #pragma unroll
        for (int kk = 0; kk < EDGE_DIM / 2; ++kk)
            s = __builtin_amdgcn_fdot2(a2[kk], w1p[c * 16 + kk], s, false);
        sil[c] = __fdividef(s, 1.0f + __expf(-s));
    }
    h2 s2[EDGE_DIM / 2];
    #pragma unroll
    for (int cc = 0; cc < EDGE_DIM / 2; ++cc)
        s2[cc] = __builtin_amdgcn_cvt_pkrtz(sil[2 * cc], sil[2 * cc + 1]);
    float b0f = be2[0], b1f = be2[1], b2f = be2[2], b3f = be2[3];
    float b4f = be2[4], b5f = be2[5], b6f = be2[6], b7f = be2[7];
    #pragma unroll
    for (int cc = 0; cc < EDGE_DIM / 2; ++cc) {
        b0f = __builtin_amdgcn_fdot2(s2[cc], w2p[0 * 16 + cc], b0f, false);
        b1f = __builtin_amdgcn_fdot2(s2[cc], w2p[1 * 16 + cc], b1f, false);
        b2f = __builtin_amdgcn_fdot2(s2[cc], w2p[2 * 16 + cc], b2f, false);
        b3f = __builtin_amdgcn_fdot2(s2[cc], w2p[3 * 16 + cc], b3f, false);
        b4f = __builtin_amdgcn_fdot2(s2[cc], w2p[4 * 16 + cc], b4f, false);
        b5f = __builtin_amdgcn_fdot2(s2[cc], w2p[5 * 16 + cc], b5f, false);
        b6f = __builtin_amdgcn_fdot2(s2[cc], w2p[6 * 16 + cc], b6f, false);
        b7f = __builtin_amdgcn_fdot2(s2[cc], w2p[7 * 16 + cc], b7f, false);
    }
    uint4 br;
    br.x = f2bf(b0f) | (f2bf(b1f) << 16);
    br.y = f2bf(b2f) | (f2bf(b3f) << 16);
    br.z = f2bf(b4f) | (f2bf(b5f) << 16);
    br.w = f2bf(b6f) | (f2bf(b7f) << 16);
    bias_by_e[e] = br;
}

// ---------------- K_A2: 8B-record bucket partition (512 thr, wave-shfl scan) ----------------
__global__ __launch_bounds__(512) void partition_only(
    const int* __restrict__ ei, int* __restrict__ gcur, uint2* __restrict__ A_rec)
{
    __shared__ int cnt[NB];
    __shared__ int base[NB];
    __shared__ int lbase[NB];
    __shared__ int wsum[8];
    __shared__ int total_s;
    __shared__ uint2 srec[PART_E];           // 16 KB
    __shared__ unsigned short sbkt[PART_E];  // 4 KB
    const int tid = threadIdx.x;
    const int lane = tid & 63;
    const int w = tid >> 6;  // 0..7
    cnt[tid] = 0;
    __syncthreads();
    const int e0 = blockIdx.x * PART_E;
    #pragma unroll
    for (int k = 0; k < EPT; ++k) {
        const int e = e0 + k * PART_T + tid;
        if (e < N_EDGES) atomicAdd(&cnt[ei[N_EDGES + e] / NPB], 1);
    }
    __syncthreads();
    // wave-shfl inclusive scan of cnt[0..511]
    int v = cnt[tid];
    #pragma unroll
    for (int o = 1; o < 64; o <<= 1) {
        int t = __shfl_up(v, o, 64);
        if (lane >= o) v += t;
    }
    if (lane == 63) wsum[w] = v;
    __syncthreads();
    int add = 0;
    #pragma unroll
    for (int ww = 0; ww < 7; ++ww) if (ww < w) add += wsum[ww];
    v += add;  // global inclusive scan
    {
        const int c = cnt[tid];
        base[tid] = (c > 0) ? atomicAdd(&gcur[tid], c) : 0;
        lbase[tid] = v - c;  // exclusive
        if (tid == NB - 1) total_s = v;
        cnt[tid] = 0;        // reuse as local cursor
    }
    __syncthreads();
    #pragma unroll
    for (int k = 0; k < EPT; ++k) {
        const int e = e0 + k * PART_T + tid;
        if (e < N_EDGES) {
            const int i = ei[e];
            const int j = ei[N_EDGES + e];
            const int b = j / NPB;
            const int jl = j - b * NPB;
            const int s = lbase[b] + atomicAdd(&cnt[b], 1);
            srec[s] = make_uint2((unsigned)e, ((unsigned)jl << 24) | (unsigned)i);
            sbkt[s] = (unsigned short)b;
        }
    }
    __syncthreads();
    const int total = total_s;
    for (int s = tid; s < total; s += PART_T) {
        const int b = sbkt[s];
        const int gp = base[b] + (s - lbase[b]);
        if (gp < ACAP) A_rec[(size_t)b * ACAP + gp] = srec[s];
    }
}

// ---------------- K_B: heterogeneous grid — perm (blocks 0..NB-1) + qkv (rest) ----------------
__global__ __launch_bounds__(256) void perm_qkv(
    const int* __restrict__ gcur, const uint2* __restrict__ A_rec,
    int* __restrict__ offs, uint2* __restrict__ es_sorted,
    const float* __restrict__ x,
    const float* __restrict__ WQ, const float* __restrict__ bQ,
    const float* __restrict__ WK, const float* __restrict__ bK,
    const float* __restrict__ WV, const float* __restrict__ bV,
    unsigned int* __restrict__ Q2, unsigned int* __restrict__ KV2)
{
    __shared__ __align__(16) char smem[3 * DIM * DIM * sizeof(float)];  // 48 KB
    const int tid = threadIdx.x;
    const int lane = tid & 63;
    const int w = tid >> 6;
    if (blockIdx.x < NB) {
        int* ldeg = (int*)smem;          // NPB
        int* loff = ldeg + NPB;          // NPB+1
        int* wsum = loff + NPB + 1;      // 4
        int* gb   = wsum + 4;            // 1
        const int b = blockIdx.x;
        // gbase = prefix sum of min(gcur[t],ACAP) for t < b (single wave)
        if (w == 0) {
            int ssum = 0;
            for (int t = lane; t < b; t += 64) ssum += min(gcur[t], ACAP);
            #pragma unroll
            for (int o = 1; o < 64; o <<= 1) ssum += __shfl_xor(ssum, o, 64);
            if (lane == 0) gb[0] = ssum;
        }
        if (tid < NPB) ldeg[tid] = 0;
        __syncthreads();
        const int gbase = gb[0];
        const int nb = min(gcur[b], ACAP);
        for (int r = tid; r < nb; r += 256)
            atomicAdd(&ldeg[A_rec[(size_t)b * ACAP + r].y >> 24], 1);
        __syncthreads();
        // wave-shfl scan of ldeg (padded to 256)
        int v = (tid < NPB) ? ldeg[tid] : 0;
        #pragma unroll
        for (int o = 1; o < 64; o <<= 1) {
            int t = __shfl_up(v, o, 64);
            if (lane >= o) v += t;
        }
        if (lane == 63) wsum[w] = v;
        __syncthreads();
        int add = 0;
        #pragma unroll
        for (int ww = 0; ww < 3; ++ww) if (ww < w) add += wsum[ww];
        v += add;
        if (tid == 0) loff[0] = 0;
        if (tid < NPB) { loff[tid + 1] = v; ldeg[tid] = 0; }  // ldeg -> cursor
        __syncthreads();
        const int jbase = b * NPB;
        if (tid < NPB && jbase + tid < N_NODES) offs[jbase + tid] = gbase + loff[tid];
        if (b == NB - 1 && tid == 0) offs[N_NODES] = gbase + nb;
        for (int r = tid; r < nb; r += 256) {
            const uint2 rec = A_rec[(size_t)b * ACAP + r];
            const int jl = (int)(rec.y >> 24);
            const int slot = loff[jl] + atomicAdd(&ldeg[jl], 1);
            es_sorted[(size_t)gbase + slot] = make_uint2(rec.x, rec.y & 0xFFFFFFu);
        }
    } else {
        float* sWQ = (float*)smem;
        float* sWK = sWQ + DIM * DIM;
        float* sWV = sWK + DIM * DIM;
        for (int t = tid; t < DIM * DIM; t += 256) {
            sWQ[t] = WQ[t]; sWK[t] = WK[t]; sWV[t] = WV[t];
        }
        __syncthreads();
        const int n = (blockIdx.x - NB) * 4 + w;
        if (n >= N_NODES) return;
        float xl = x[(size_t)n * DIM + lane];
        float aq = bQ[lane], ak = bK[lane], av = bV[lane];
        #pragma unroll
        for (int k = 0; k < DIM; ++k) {
            float xv = __shfl(xl, k, 64);
            aq += xv * sWQ[k * DIM + lane];
            ak += xv * sWK[k * DIM + lane];
            av += xv * sWV[k * DIM + lane];
        }
        const int s = lane & 31;
        const float aq_e = __shfl(aq, 2 * s, 64);
        const float aq_o = __shfl(aq, 2 * s + 1, 64);
        const float ak_e = __shfl(ak, 2 * s, 64);
        const float ak_o = __shfl(ak, 2 * s + 1, 64);
        const float av_e = __shfl(av, 2 * s, 64);
        const float av_o = __shfl(av, 2 * s + 1, 64);
        if (lane < 32) {
            Q2[(size_t)n * 32 + s]  = h2u(__builtin_amdgcn_cvt_pkrtz(aq_e, aq_o));
            KV2[(size_t)n * 64 + s] = h2u(__builtin_amdgcn_cvt_pkrtz(ak_e, ak_o));
        } else {
            KV2[(size_t)n * 64 + 32 + s] = f2bf(av_e) | (f2bf(av_o) << 16);
        }
    }
}

// ---------------- K3: per-node attention + fused out-proj, paired-dim fdot2 ----------------
__global__ __launch_bounds__(256) void node_attn_out(
    const int* __restrict__ off,
    const uint2* __restrict__ es_sorted,
    const unsigned short* __restrict__ bias_u16,
    const unsigned int* __restrict__ Q2, const unsigned int* __restrict__ KV2,
    const float* __restrict__ WO, const float* __restrict__ bO,
    float* __restrict__ out)
{
    __shared__ float sWO[DIM * DIM];
    for (int t = threadIdx.x; t < DIM * DIM; t += 256) sWO[t] = WO[t];
    __syncthreads();
    const int lane = threadIdx.x & 63;
    const int wave = threadIdx.x >> 6;
    const int j = blockIdx.x * 4 + wave;
    if (j >= N_NODES) return;
    const int beg = off[j], end = off[j + 1];
    const int s = lane & 31;
    const int half = lane >> 5;
    const int h = s >> 2;
    const float inv_sqrt_dk = 0.35355339059327373f;
    const h2 q2 = u2h(Q2[(size_t)j * 32 + s]);
    float num2x = 0.0f, num2y = 0.0f;
    float den = 1e-12f;
    int t = beg;
    for (; t + 7 < end; t += 8) {
        uint2 r[4];
        unsigned int k2v[4], v2v[4];
        float bb[4], d[4];
        #pragma unroll
        for (int q = 0; q < 4; ++q) r[q] = es_sorted[t + 2 * q + half];
        #pragma unroll
        for (int q = 0; q < 4; ++q) k2v[q] = KV2[(size_t)r[q].y * 64 + s];
        #pragma unroll
        for (int q = 0; q < 4; ++q) v2v[q] = KV2[(size_t)r[q].y * 64 + 32 + s];
        #pragma unroll
        for (int q = 0; q < 4; ++q)
            bb[q] = bf_lo((unsigned int)bias_u16[(size_t)r[q].x * HEADS + h]);
        #pragma unroll
        for (int q = 0; q < 4; ++q)
            d[q] = __builtin_amdgcn_fdot2(q2, u2h(k2v[q]), 0.0f, false);
        #pragma unroll
        for (int q = 0; q < 4; ++q) d[q] += __shfl_xor(d[q], 1, 64);
        #pragma unroll
        for (int q = 0; q < 4; ++q) d[q] += __shfl_xor(d[q], 2, 64);
        #pragma unroll
        for (int q = 0; q < 4; ++q) {
            const float ev = __expf(d[q] * inv_sqrt_dk + bb[q]);
            num2x += ev * bf_lo(v2v[q]);
            num2y += ev * bf_hi(v2v[q]);
            den += ev;
        }
    }
    for (; t + 1 < end; t += 2) {
        const uint2 r0 = es_sorted[t + half];
        const unsigned int k2v = KV2[(size_t)r0.y * 64 + s];
        const unsigned int v2v = KV2[(size_t)r0.y * 64 + 32 + s];
        const float bb = bf_lo((unsigned int)bias_u16[(size_t)r0.x * HEADS + h]);
        float d = __builtin_amdgcn_fdot2(q2, u2h(k2v), 0.0f, false);
        d += __shfl_xor(d, 1, 64);
        d += __shfl_xor(d, 2, 64);
        const float ev = __expf(d * inv_sqrt_dk + bb);
        num2x += ev * bf_lo(v2v);
        num2y += ev * bf_hi(v2v);
        den += ev;
    }
    if (t < end) {  // odd tail: only half 0 contributes
        const uint2 r0 = es_sorted[t];
        const unsigned int k2v = KV2[(size_t)r0.y * 64 + s];
        const unsigned int v2v = KV2[(size_t)r0.y * 64 + 32 + s];
        const float bb = bf_lo((unsigned int)bias_u16[(size_t)r0.x * HEADS + h]);
        float d = __builtin_amdgcn_fdot2(q2, u2h(k2v), 0.0f, false);
        d += __shfl_xor(d, 1, 64);
        d += __shfl_xor(d, 2, 64);
        float ev = __expf(d * inv_sqrt_dk + bb);
        if (half != 0) ev = 0.0f;
        num2x += ev * bf_lo(v2v);
        num2y += ev * bf_hi(v2v);
        den += ev;
    }
    num2x += __shfl_xor(num2x, 32, 64);
    num2y += __shfl_xor(num2y, 32, 64);
    den   += __shfl_xor(den, 32, 64);
    const float av2x = num2x / den;
    const float av2y = num2y / den;
    float acc = bO[lane];
    #pragma unroll
    for (int sp = 0; sp < 32; ++sp) {
        acc += __shfl(av2x, sp, 64) * sWO[(2 * sp) * DIM + lane];
        acc += __shfl(av2y, sp, 64) * sWO[(2 * sp + 1) * DIM + lane];
    }
    out[(size_t)j * DIM + lane] = acc;
}

extern "C" void kernel_launch(void* const* d_in, const int* in_sizes, int n_in,
                              void* d_out, int out_size, void* d_ws, size_t ws_size,
                              hipStream_t stream) {
    const float* x    = (const float*)d_in[0];
    const int*   ei   = (const int*)d_in[1];
    const float* ea   = (const float*)d_in[2];
    const float* WQ   = (const float*)d_in[3];
    const float* bQ   = (const float*)d_in[4];
    const float* WK   = (const float*)d_in[5];
    const float* bK   = (const float*)d_in[6];
    const float* WV   = (const float*)d_in[7];
    const float* bV   = (const float*)d_in[8];
    const float* WO   = (const float*)d_in[9];
    const float* bO   = (const float*)d_in[10];
    const float* We1  = (const float*)d_in[11];
    const float* be1  = (const float*)d_in[12];
    const float* We2  = (const float*)d_in[13];
    const float* be2  = (const float*)d_in[14];
    float* out = (float*)d_out;

    char* ws = (char*)d_ws;
    size_t off_b = 0;
    auto alloc = [&](size_t bytes) {
        void* p = ws + off_b;
        off_b += (bytes + 255) & ~(size_t)255;
        return p;
    };
    unsigned int* Q2        = (unsigned int*)alloc((size_t)N_NODES * 32 * sizeof(unsigned int));
    unsigned int* KV2       = (unsigned int*)alloc((size_t)N_NODES * 64 * sizeof(unsigned int));
    uint2*        A_rec     = (uint2*)alloc((size_t)NB * ACAP * sizeof(uint2));
    uint4*        bias_by_e = (uint4*)alloc((size_t)N_EDGES * sizeof(uint4));
    uint2*        es_sorted = (uint2*)alloc((size_t)N_EDGES * sizeof(uint2));
    int*          offs      = (int*)alloc((size_t)(N_NODES + 1) * sizeof(int));
    int*          gcur      = (int*)alloc((size_t)NB * sizeof(int));
    h2*           w1p       = (h2*)alloc(512 * sizeof(h2));
    h2*           w2p       = (h2*)alloc(128 * sizeof(h2));

    pack_weights<<<1, 1024, 0, stream>>>(We1, We2, w1p, w2p, gcur);
    partition_only<<<(N_EDGES + PART_E - 1) / PART_E, PART_T, 0, stream>>>(ei, gcur, A_rec);
    mlp_only<<<(N_EDGES + 255) / 256, 256, 0, stream>>>(ea, w1p, be1, w2p, be2, bias_by_e);
    perm_qkv<<<NB + QKV_BLKS, 256, 0, stream>>>(gcur, A_rec, offs, es_sorted,
                                                x, WQ, bQ, WK, bK, WV, bV, Q2, KV2);
    node_attn_out<<<(N_NODES + 3) / 4, 256, 0, stream>>>(offs, es_sorted,
                                                         (const unsigned short*)bias_by_e,
                                                         Q2, KV2, WO, bO, out);
}